// Round 5
// baseline (225.068 us; speedup 1.0000x reference)
//
#include <hip/hip_runtime.h>

#define B_ 4
#define S_ 2048
#define H_ 2048
#define R_ 64
#define DKV_ 1024

typedef __attribute__((ext_vector_type(8))) short s16x8;
typedef __attribute__((ext_vector_type(4))) float f32x4v;

__device__ __forceinline__ unsigned short f2bf(float x) {
  unsigned int u = __builtin_bit_cast(unsigned int, x);
  u += 0x7FFF + ((u >> 16) & 1);
  return (unsigned short)(u >> 16);
}
__device__ __forceinline__ float bf2f(unsigned short h) {
  unsigned int u = ((unsigned int)h) << 16;
  return __builtin_bit_cast(float, u);
}

__device__ __forceinline__ void gl_lds16(const void* g, void* l) {
  __builtin_amdgcn_global_load_lds(
      (const __attribute__((address_space(1))) unsigned int*)g,
      (__attribute__((address_space(3))) unsigned int*)l, 16, 0, 0);
}

// swizzled byte offset within a [rows][32 bf16] LDS tile (2-way max bank alias)
__device__ __forceinline__ int swz_off(int m, int kb) {
  int L = m >> 1;
  int slot = ((m & 1) << 2) | (kb >> 4);
  int sp = slot ^ (L & 7);
  return (L << 7) | (sp << 4) | (kb & 15);
}

// ---------------- fp32 -> bf16 hi + lo split ----------------
__global__ __launch_bounds__(256) void k_f32_to_bf16x2(const float* __restrict__ in,
    unsigned short* __restrict__ hi, unsigned short* __restrict__ lo, int n4) {
  int i = blockIdx.x * 256 + threadIdx.x;
  if (i >= n4) return;
  float4 v = ((const float4*)in)[i];
  ushort4 h, l;
  h.x = f2bf(v.x); h.y = f2bf(v.y); h.z = f2bf(v.z); h.w = f2bf(v.w);
  l.x = f2bf(v.x - bf2f(h.x)); l.y = f2bf(v.y - bf2f(h.y));
  l.z = f2bf(v.z - bf2f(h.z)); l.w = f2bf(v.w - bf2f(h.w));
  ((ushort4*)hi)[i] = h;
  ((ushort4*)lo)[i] = l;
}

// ---------------- transpose fp32 [rows][cols] -> bf16 [cols][rows] ----------------
__global__ __launch_bounds__(256) void k_transpose_bf16(const float* __restrict__ in,
    unsigned short* __restrict__ out, int rows, int cols) {
  __shared__ float tile[32][33];
  int c0 = blockIdx.x * 32, r0 = blockIdx.y * 32;
  int tx = threadIdx.x & 31, ty = threadIdx.x >> 5;
  for (int i = 0; i < 4; ++i)
    tile[ty + i * 8][tx] = in[(size_t)(r0 + ty + i * 8) * cols + c0 + tx];
  __syncthreads();
  for (int i = 0; i < 4; ++i)
    out[(size_t)(c0 + ty + i * 8) * rows + r0 + tx] = f2bf(tile[tx][ty + i * 8]);
}

// ---------------- WqkT hi/lo: [128 n][2048 k] from Wq,Wk [2048][64] ----------------
__global__ __launch_bounds__(256) void k_build_wqkt(const float* __restrict__ Wq,
    const float* __restrict__ Wk, unsigned short* __restrict__ hiT,
    unsigned short* __restrict__ loT) {
  __shared__ float tile[32][33];
  int k0 = blockIdx.x * 32, n0 = blockIdx.y * 32;
  const float* W = (n0 < 64) ? Wq : Wk;
  int nb = n0 & 63;
  int tx = threadIdx.x & 31, ty = threadIdx.x >> 5;
  for (int i = 0; i < 4; ++i)
    tile[ty + i * 8][tx] = W[(size_t)(k0 + ty + i * 8) * R_ + nb + tx];
  __syncthreads();
  for (int i = 0; i < 4; ++i) {
    float v = tile[tx][ty + i * 8];
    unsigned short h = f2bf(v);
    size_t idx = (size_t)(n0 + ty + i * 8) * H_ + k0 + tx;
    hiT[idx] = h;
    loT[idx] = f2bf(v - bf2f(h));
  }
}

// ---------------- WoT_eff[n][r] = Wo[h1(r)][n] + Wo[h1(r)+128][n], bf16 ----------------
__global__ __launch_bounds__(256) void k_build_wot(const float* __restrict__ Wo,
                                                   unsigned short* __restrict__ WoT) {
  __shared__ float tile[32][33];
  int n0 = blockIdx.x * 32, r0 = blockIdx.y * 32;
  int h1b = 256 * (r0 >> 7) + (r0 & 127);
  int tx = threadIdx.x & 31, ty = threadIdx.x >> 5;
  for (int i = 0; i < 4; ++i) {
    int dr = ty + i * 8;
    tile[dr][tx] = Wo[(size_t)(h1b + dr) * H_ + n0 + tx] +
                   Wo[(size_t)(h1b + 128 + dr) * H_ + n0 + tx];
  }
  __syncthreads();
  for (int i = 0; i < 4; ++i)
    WoT[(size_t)(n0 + ty + i * 8) * DKV_ + r0 + tx] = f2bf(tile[tx][ty + i * 8]);
}

// ---------------- q/k projection via split-bf16 MFMA; 3-buffer counted-vmcnt pipeline ----------------
__global__ __launch_bounds__(256) void k_qk_mfma(
    const unsigned short* __restrict__ Ahi, const unsigned short* __restrict__ Alo,
    const unsigned short* __restrict__ Bhi, const unsigned short* __restrict__ Blo,
    unsigned short* __restrict__ qkh, unsigned short* __restrict__ qkl) {
  // per-buffer layout: AsH[0,2K) AsL[2K,4K) BsH[4K,12K) BsL[12K,20K)
  constexpr int TQK = 20480;
  __shared__ __attribute__((aligned(16))) char lds[3 * TQK];
  int m0 = blockIdx.x * 32;
  int t = threadIdx.x;
  int lane = t & 63, wave = t >> 6;
  int lr = lane & 15, kb = (lane >> 4) << 4;

  auto stage = [&](int kt, int buf) {
    int k0 = kt << 5;
    char* base = &lds[buf * TQK];
    {  // A hi (waves 0,1) / lo (waves 2,3): 128 chunks each
      int q = t & 127;
      int L = q >> 3;
      int slot = (q & 7) ^ (L & 7);
      int m = (L << 1) | (slot >> 2);
      int ke = (slot & 3) << 3;
      const unsigned short* src =
          (t < 128 ? Ahi : Alo) + (size_t)(m0 + m) * H_ + k0 + ke;
      gl_lds16(src, base + (t < 128 ? 0 : 2048) + q * 16);
    }
#pragma unroll
    for (int c = 0; c < 2; ++c) {  // B hi: 512 chunks
      int q = c * 256 + t;
      int L = q >> 3;
      int slot = (q & 7) ^ (L & 7);
      int n = (L << 1) | (slot >> 2);
      int ke = (slot & 3) << 3;
      gl_lds16(Bhi + (size_t)n * H_ + k0 + ke, base + 4096 + q * 16);
    }
#pragma unroll
    for (int c = 0; c < 2; ++c) {  // B lo: 512 chunks
      int q = c * 256 + t;
      int L = q >> 3;
      int slot = (q & 7) ^ (L & 7);
      int n = (L << 1) | (slot >> 2);
      int ke = (slot & 3) << 3;
      gl_lds16(Blo + (size_t)n * H_ + k0 + ke, base + 12288 + q * 16);
    }
  };

  f32x4v acc[2][2] = {};
  stage(0, 0);
  stage(1, 1);
  int cur = 0, nxt = 2;
  for (int kt = 0; kt < 64; ++kt) {
    __builtin_amdgcn_sched_barrier(0);
    if (kt < 63) asm volatile("s_waitcnt vmcnt(5)" ::: "memory");
    else asm volatile("s_waitcnt vmcnt(0)" ::: "memory");
    __builtin_amdgcn_s_barrier();
    __builtin_amdgcn_sched_barrier(0);
    if (kt + 2 < 64) stage(kt + 2, nxt);
    const char* base = &lds[cur * TQK];
    s16x8 ah[2], al[2], bh[2], bl[2];
#pragma unroll
    for (int m = 0; m < 2; ++m) {
      int o = swz_off(m * 16 + lr, kb);
      ah[m] = *(const s16x8*)(base + o);
      al[m] = *(const s16x8*)(base + 2048 + o);
    }
#pragma unroll
    for (int n = 0; n < 2; ++n) {
      int o = swz_off(wave * 32 + n * 16 + lr, kb);
      bh[n] = *(const s16x8*)(base + 4096 + o);
      bl[n] = *(const s16x8*)(base + 12288 + o);
    }
    __builtin_amdgcn_s_setprio(1);
#pragma unroll
    for (int m = 0; m < 2; ++m)
#pragma unroll
      for (int n = 0; n < 2; ++n) {
        acc[m][n] = __builtin_amdgcn_mfma_f32_16x16x32_bf16(ah[m], bh[n], acc[m][n], 0, 0, 0);
        acc[m][n] = __builtin_amdgcn_mfma_f32_16x16x32_bf16(ah[m], bl[n], acc[m][n], 0, 0, 0);
        acc[m][n] = __builtin_amdgcn_mfma_f32_16x16x32_bf16(al[m], bh[n], acc[m][n], 0, 0, 0);
      }
    __builtin_amdgcn_s_setprio(0);
    cur = (cur == 2) ? 0 : cur + 1;
    nxt = (nxt == 2) ? 0 : nxt + 1;
  }
  for (int m = 0; m < 2; ++m) {
    int lrow = m * 16 + ((lane >> 4) << 2);
    for (int n = 0; n < 2; ++n) {
      int lcol = wave * 32 + n * 16 + lr;
      for (int r = 0; r < 4; ++r) {
        float v = acc[m][n][r];
        unsigned short h = f2bf(v);
        size_t idx = (size_t)(m0 + lrow + r) * 128 + lcol;
        qkh[idx] = h;
        qkl[idx] = f2bf(v - bf2f(h));
      }
    }
  }
}

// ---------------- scores via split-bf16 MFMA + exp + partial rowsums ----------------
__global__ __launch_bounds__(256) void k_scores_mfma(
    const unsigned short* __restrict__ qkh, const unsigned short* __restrict__ qkl,
    unsigned short* __restrict__ probs, float* __restrict__ part) {
  __shared__ unsigned short AsH[128 * 32], AsL[128 * 32];
  __shared__ unsigned short BsH[128 * 32], BsL[128 * 32];
  __shared__ float psum[128];
  int tri = blockIdx.x, b = blockIdx.y;
  int t = threadIdx.x;
  int it = (int)((sqrtf(8.f * tri + 1.f) - 1.f) * 0.5f);
  while ((it + 1) * (it + 2) / 2 <= tri) ++it;
  while (it * (it + 1) / 2 > tri) --it;
  int jt = tri - it * (it + 1) / 2;
  int i0 = it * 128, j0 = jt * 128;
  const unsigned short* Ah = qkh + (size_t)(b * S_ + i0) * 128;
  const unsigned short* Al = qkl + (size_t)(b * S_ + i0) * 128;
  const unsigned short* Bh = qkh + (size_t)(b * S_ + j0) * 128 + 64;
  const unsigned short* Bl = qkl + (size_t)(b * S_ + j0) * 128 + 64;
  if (t < 128) psum[t] = 0.f;
  int lane = t & 63, wave = t >> 6;
  int wr = wave >> 1, wc = wave & 1;
  int lr = lane & 15, lk = (lane >> 4) * 8;
  f32x4v acc[4][4] = {};
  for (int k0 = 0; k0 < 64; k0 += 32) {
    for (int c = 0; c < 2; ++c) {
      int id = c * 256 + t;
      int row = id >> 2, kc = (id & 3) * 8;
      gl_lds16(Ah + (size_t)row * 128 + k0 + kc, &AsH[row * 32 + kc]);
      gl_lds16(Al + (size_t)row * 128 + k0 + kc, &AsL[row * 32 + kc]);
      gl_lds16(Bh + (size_t)row * 128 + k0 + kc, &BsH[row * 32 + kc]);
      gl_lds16(Bl + (size_t)row * 128 + k0 + kc, &BsL[row * 32 + kc]);
    }
    __syncthreads();
    s16x8 ah[4], al[4], bh[4], bl[4];
    for (int m = 0; m < 4; ++m) {
      ah[m] = *(const s16x8*)&AsH[(wr * 64 + m * 16 + lr) * 32 + lk];
      al[m] = *(const s16x8*)&AsL[(wr * 64 + m * 16 + lr) * 32 + lk];
    }
    for (int n = 0; n < 4; ++n) {
      bh[n] = *(const s16x8*)&BsH[(wc * 64 + n * 16 + lr) * 32 + lk];
      bl[n] = *(const s16x8*)&BsL[(wc * 64 + n * 16 + lr) * 32 + lk];
    }
    for (int m = 0; m < 4; ++m)
      for (int n = 0; n < 4; ++n) {
        acc[m][n] = __builtin_amdgcn_mfma_f32_16x16x32_bf16(ah[m], bh[n], acc[m][n], 0, 0, 0);
        acc[m][n] = __builtin_amdgcn_mfma_f32_16x16x32_bf16(ah[m], bl[n], acc[m][n], 0, 0, 0);
        acc[m][n] = __builtin_amdgcn_mfma_f32_16x16x32_bf16(al[m], bh[n], acc[m][n], 0, 0, 0);
      }
    __syncthreads();
  }
  unsigned short* Pp = probs + (size_t)b * S_ * S_;
  for (int m = 0; m < 4; ++m) {
    int lrow = wr * 64 + m * 16 + ((lane >> 4) << 2);
    float ps[4] = {0.f, 0.f, 0.f, 0.f};
    for (int n = 0; n < 4; ++n) {
      int j = j0 + wc * 64 + n * 16 + lr;
      for (int r = 0; r < 4; ++r) {
        int i = i0 + lrow + r;
        float p = (j <= i) ? __expf(acc[m][n][r]) : 0.f;
        ps[r] += p;
        Pp[(size_t)i * S_ + j] = f2bf(p);
      }
    }
    for (int r = 0; r < 4; ++r) {
      float v = ps[r];
      for (int msk = 1; msk < 16; msk <<= 1) v += __shfl_xor(v, msk, 64);
      if (lr == 0) atomicAdd(&psum[lrow + r], v);
    }
  }
  __syncthreads();
  if (t < 128) part[(size_t)(b * 16 + jt) * S_ + i0 + t] = psum[t];
}

// ---------------- rowsum reduce + reciprocal ----------------
__global__ __launch_bounds__(256) void k_rowsum_recip(const float* __restrict__ part,
                                                      float* __restrict__ recip) {
  int g = blockIdx.x * 256 + threadIdx.x;
  int b = g >> 11, i = g & (S_ - 1);
  int it = i >> 7;
  float s = 0.f;
  for (int jt = 0; jt <= it; ++jt) s += part[(size_t)(b * 16 + jt) * S_ + i];
  recip[(size_t)b * S_ + i] = 1.f / s;
}

// ---------------- pipelined bf16 MFMA GEMM ----------------
// C[m][n] = sum_k A[m][k] * BT[n][k]; 512 threads, 8 waves, BK=32,
// 3-buffer LDS pipeline, counted vmcnt depth-2, swizzled LDS.
// Wave decomposition (serial-model driven: util = MFMA/(MFMA + (WM+WN) LDS reads)):
//   BM=256,BN=256: waves 2Mx4N -> wave tile 128x64 (2.67 MFMA/b128, best)
//   BM=256,BN=128: waves 4Mx2N -> wave tile 64x64  (2.0)
//   BM=128,BN=256: waves 2Mx4N -> wave tile 64x64  (2.0)
template <int BM, int BN, bool TRANS_OUT, bool OUT_BF16, bool SCALE, bool CAUSAL,
          int WPEU>
__global__ __launch_bounds__(512, WPEU) void k_gemm256(
    const unsigned short* __restrict__ A, int lda, long batchA,
    const unsigned short* __restrict__ BT, int ldbt, long batchBT,
    void* __restrict__ C, int ldc, long batchC,
    const float* __restrict__ recip, int batchR, int K) {
  constexpr int ABYTES = BM * 64;
  constexpr int BBYTES = BN * 64;
  constexpr int TILEB = ABYTES + BBYTES;
  constexpr int WARPS_M = (BM == 256 && BN == 256) ? 2 : ((BM >= 256) ? 4 : 2);
  constexpr int WARPS_N = 8 / WARPS_M;
  constexpr int WM = BM / WARPS_M;
  constexpr int WN = BN / WARPS_N;
  constexpr int MF = WM / 16;
  constexpr int NF = WN / 16;
  constexpr int LPS = BM / 128 + BN / 128;  // loads per thread per stage
  __shared__ __attribute__((aligned(16))) char lds[3 * TILEB];
  __shared__ float s_recip[BM];

  int t = threadIdx.x;
  int gx = gridDim.x;
  int bx, by;
  if (CAUSAL) {
    int x = blockIdx.x;
    bx = (x & 1) ? (gx - 1 - (x >> 1)) : (x >> 1);  // consecutive ids: heavy+light
    if (blockIdx.z & 2) bx = gx - 1 - bx;           // stride-256 ids: heavy+light
    by = blockIdx.y;
  } else {
    int id = blockIdx.y * gx + blockIdx.x;
    int cpx = gx >> 3;  // gridDim.x must be a multiple of 8
    int xcd = id & 7, rr = id >> 3;
    bx = xcd * cpx + rr % cpx;  // contiguous bx-chunk per XCD, all by
    by = rr / cpx;
  }
  int z = blockIdx.z;
  int m0 = bx * BM, n0 = by * BN;

  const unsigned short* Ab = A + (long)z * batchA + (size_t)m0 * lda;
  const unsigned short* Bb = BT + (long)z * batchBT + (size_t)n0 * ldbt;

  if (SCALE && t < BM) s_recip[t] = recip[(long)z * batchR + m0 + t];

  int lane = t & 63, wave = t >> 6;
  int wr = wave / WARPS_N, wc = wave % WARPS_N;
  int kb = (lane >> 4) << 4;
  int aoff[MF], boff[NF];
#pragma unroll
  for (int mf = 0; mf < MF; ++mf)
    aoff[mf] = swz_off(wr * WM + mf * 16 + (lane & 15), kb);
#pragma unroll
  for (int nf = 0; nf < NF; ++nf)
    boff[nf] = swz_off(wc * WN + nf * 16 + (lane & 15), kb);

  int NT = (CAUSAL ? (m0 + BM) : K) >> 5;

  auto stage = [&](int kt, int buf) {
    int k0 = kt << 5;
    char* la = &lds[buf * TILEB];
    char* lb = la + ABYTES;
#pragma unroll
    for (int c = 0; c < BM / 128; ++c) {
      int q = c * 512 + t;
      int L = q >> 3;
      int slot = (q & 7) ^ (L & 7);
      int m = (L << 1) | (slot >> 2);
      int ke = (slot & 3) << 3;
      gl_lds16(Ab + (size_t)m * lda + k0 + ke, la + q * 16);
    }
#pragma unroll
    for (int c = 0; c < BN / 128; ++c) {
      int q = c * 512 + t;
      int L = q >> 3;
      int slot = (q & 7) ^ (L & 7);
      int n = (L << 1) | (slot >> 2);
      int ke = (slot & 3) << 3;
      gl_lds16(Bb + (size_t)n * ldbt + k0 + ke, lb + q * 16);
    }
  };

  f32x4v acc[MF][NF] = {};
  stage(0, 0);
  if (NT > 1) stage(1, 1);
  int cur = 0, nxt = 2;
  for (int kt = 0; kt < NT; ++kt) {
    __builtin_amdgcn_sched_barrier(0);
    if (kt + 1 < NT) {
      if constexpr (LPS == 2) asm volatile("s_waitcnt vmcnt(2)" ::: "memory");
      else if constexpr (LPS == 3) asm volatile("s_waitcnt vmcnt(3)" ::: "memory");
      else asm volatile("s_waitcnt vmcnt(4)" ::: "memory");
    } else {
      asm volatile("s_waitcnt vmcnt(0)" ::: "memory");
    }
    __builtin_amdgcn_s_barrier();
    __builtin_amdgcn_sched_barrier(0);
    if (kt + 2 < NT) stage(kt + 2, nxt);
    const char* la = &lds[cur * TILEB];
    const char* lb = la + ABYTES;
    s16x8 af[MF], bf[NF];
#pragma unroll
    for (int mf = 0; mf < MF; ++mf) af[mf] = *(const s16x8*)(la + aoff[mf]);
#pragma unroll
    for (int nf = 0; nf < NF; ++nf) bf[nf] = *(const s16x8*)(lb + boff[nf]);
    __builtin_amdgcn_s_setprio(1);
#pragma unroll
    for (int mf = 0; mf < MF; ++mf)
#pragma unroll
      for (int nf = 0; nf < NF; ++nf)
        acc[mf][nf] =
            __builtin_amdgcn_mfma_f32_16x16x32_bf16(af[mf], bf[nf], acc[mf][nf], 0, 0, 0);
    __builtin_amdgcn_s_setprio(0);
    cur = (cur == 2) ? 0 : cur + 1;
    nxt = (nxt == 2) ? 0 : nxt + 1;
  }

#pragma unroll
  for (int mf = 0; mf < MF; ++mf) {
    int lrow = wr * WM + mf * 16 + ((lane >> 4) << 2);
#pragma unroll
    for (int nf = 0; nf < NF; ++nf) {
      int lcol = wc * WN + nf * 16 + (lane & 15);
      f32x4v v = acc[mf][nf];
      if (TRANS_OUT) {
        float f0 = v[0], f1 = v[1], f2 = v[2], f3 = v[3];
        if (SCALE) {
          f0 *= s_recip[lrow]; f1 *= s_recip[lrow + 1];
          f2 *= s_recip[lrow + 2]; f3 *= s_recip[lrow + 3];
        }
        ushort4 o;
        o.x = f2bf(f0); o.y = f2bf(f1); o.z = f2bf(f2); o.w = f2bf(f3);
        unsigned short* Cp = (unsigned short*)C + (long)z * batchC;
        *(ushort4*)&Cp[(size_t)(n0 + lcol) * ldc + m0 + lrow] = o;
      } else {
#pragma unroll
        for (int r = 0; r < 4; ++r) {
          float f = v[r];
          if (SCALE) f *= s_recip[lrow + r];
          if (OUT_BF16) {
            unsigned short* Cp = (unsigned short*)C + (long)z * batchC;
            Cp[(size_t)(m0 + lrow + r) * ldc + n0 + lcol] = f2bf(f);
          } else {
            float* Cp = (float*)C + (long)z * batchC;
            Cp[(size_t)(m0 + lrow + r) * ldc + n0 + lcol] = f;
          }
        }
      }
    }
  }
}

extern "C" void kernel_launch(void* const* d_in, const int* in_sizes, int n_in,
                              void* d_out, int out_size, void* d_ws, size_t ws_size,
                              hipStream_t stream) {
  const float* hs = (const float*)d_in[0];
  const float* Wq = (const float*)d_in[2];
  const float* Wk = (const float*)d_in[3];
  const float* Wv = (const float*)d_in[4];
  const float* Wo = (const float*)d_in[5];
  float* out = (float*)d_out;

  char* w = (char*)d_ws;
  unsigned short* hsb = (unsigned short*)w; w += (size_t)B_ * S_ * H_ * 2;
  unsigned short* hsl = (unsigned short*)w; w += (size_t)B_ * S_ * H_ * 2;
  unsigned short* WvT = (unsigned short*)w; w += (size_t)DKV_ * H_ * 2;
  unsigned short* WoT = (unsigned short*)w; w += (size_t)H_ * DKV_ * 2;
  unsigned short* WqkTh = (unsigned short*)w; w += (size_t)128 * H_ * 2;
  unsigned short* WqkTl = (unsigned short*)w; w += (size_t)128 * H_ * 2;
  unsigned short* VT  = (unsigned short*)w; w += (size_t)DKV_ * B_ * S_ * 2;
  unsigned short* probs = (unsigned short*)w; w += (size_t)B_ * S_ * S_ * 2;
  unsigned short* ctx = (unsigned short*)w; w += (size_t)B_ * S_ * DKV_ * 2;
  unsigned short* qkh = (unsigned short*)w; w += (size_t)B_ * S_ * 128 * 2;
  unsigned short* qkl = (unsigned short*)w; w += (size_t)B_ * S_ * 128 * 2;
  float* part = (float*)w; w += (size_t)B_ * 16 * S_ * 4;
  float* recip = (float*)w; w += (size_t)B_ * S_ * 4;

  // 1) hs -> bf16 hi + lo
  k_f32_to_bf16x2<<<(B_ * S_ * H_ / 4 + 255) / 256, 256, 0, stream>>>(
      hs, hsb, hsl, B_ * S_ * H_ / 4);
  // 2) WvT = Wv^T bf16
  k_transpose_bf16<<<dim3(DKV_ / 32, H_ / 32), 256, 0, stream>>>(Wv, WvT, H_, DKV_);
  // 3) WoT_eff
  k_build_wot<<<dim3(H_ / 32, DKV_ / 32), 256, 0, stream>>>(Wo, WoT);
  // 4) WqkT hi/lo
  k_build_wqkt<<<dim3(H_ / 32, 4), 256, 0, stream>>>(Wq, Wk, WqkTh, WqkTl);
  // 5) q/k projection -> bf16 hi/lo q,k (pipelined)
  k_qk_mfma<<<B_ * S_ / 32, 256, 0, stream>>>(hsb, hsl, WqkTh, WqkTl, qkh, qkl);
  // 6) V projection (transposed epilogue -> VT): BM=256xBN=128, wave 64x64, 256 blocks
  k_gemm256<256, 128, true, true, false, false, 4>
      <<<dim3(B_ * S_ / 256, DKV_ / 128, 1), 512, 0, stream>>>(
      hsb, H_, 0, WvT, H_, 0, VT, B_ * S_, 0, nullptr, 0, H_);
  // 7) scores (lower-triangle tiles) + exp + partial rowsums
  k_scores_mfma<<<dim3(136, B_), 256, 0, stream>>>(qkh, qkl, probs, part);
  // 8) rowsum reduce -> recip
  k_rowsum_recip<<<B_ * S_ / 256, 256, 0, stream>>>(part, recip);
  // 9) PV (causal K limit, scaled): BM=128xBN=256, wave 64x64, heavy/light pairing
  k_gemm256<128, 256, false, true, true, true, 4>
      <<<dim3(S_ / 128, DKV_ / 256, B_), 512, 0, stream>>>(
      probs, S_, (long)S_ * S_, VT, B_ * S_, S_, ctx, DKV_, (long)S_ * DKV_, recip, S_, S_);
  // 10) out = ctx @ WoT^T (fp32 out): BM=256xBN=256, wave 128x64 (m201 shape), 256 blocks
  k_gemm256<256, 256, false, false, false, false, 2>
      <<<dim3(B_ * S_ / 256, H_ / 256, 1), 512, 0, stream>>>(
      ctx, DKV_, 0, WoT, DKV_, 0, out, H_, 0, nullptr, 0, DKV_);
}

// Round 6
// 201.783 us; speedup vs baseline: 1.1154x; 1.1154x over previous
//
#include <hip/hip_runtime.h>

#define B_ 4
#define S_ 2048
#define H_ 2048
#define R_ 64
#define DKV_ 1024

typedef __attribute__((ext_vector_type(8))) short s16x8;
typedef __attribute__((ext_vector_type(4))) float f32x4v;

__device__ __forceinline__ unsigned short f2bf(float x) {
  unsigned int u = __builtin_bit_cast(unsigned int, x);
  u += 0x7FFF + ((u >> 16) & 1);
  return (unsigned short)(u >> 16);
}
__device__ __forceinline__ float bf2f(unsigned short h) {
  unsigned int u = ((unsigned int)h) << 16;
  return __builtin_bit_cast(float, u);
}

__device__ __forceinline__ void gl_lds16(const void* g, void* l) {
  __builtin_amdgcn_global_load_lds(
      (const __attribute__((address_space(1))) unsigned int*)g,
      (__attribute__((address_space(3))) unsigned int*)l, 16, 0, 0);
}

// swizzled byte offset within a [rows][32 bf16] LDS tile (2-way max bank alias)
__device__ __forceinline__ int swz_off(int m, int kb) {
  int L = m >> 1;
  int slot = ((m & 1) << 2) | (kb >> 4);
  int sp = slot ^ (L & 7);
  return (L << 7) | (sp << 4) | (kb & 15);
}

// ---------------- fp32 -> bf16 hi + lo split ----------------
__global__ __launch_bounds__(256) void k_f32_to_bf16x2(const float* __restrict__ in,
    unsigned short* __restrict__ hi, unsigned short* __restrict__ lo, int n4) {
  int i = blockIdx.x * 256 + threadIdx.x;
  if (i >= n4) return;
  float4 v = ((const float4*)in)[i];
  ushort4 h, l;
  h.x = f2bf(v.x); h.y = f2bf(v.y); h.z = f2bf(v.z); h.w = f2bf(v.w);
  l.x = f2bf(v.x - bf2f(h.x)); l.y = f2bf(v.y - bf2f(h.y));
  l.z = f2bf(v.z - bf2f(h.z)); l.w = f2bf(v.w - bf2f(h.w));
  ((ushort4*)hi)[i] = h;
  ((ushort4*)lo)[i] = l;
}

// ---------------- transpose fp32 [rows][cols] -> bf16 [cols][rows] ----------------
__global__ __launch_bounds__(256) void k_transpose_bf16(const float* __restrict__ in,
    unsigned short* __restrict__ out, int rows, int cols) {
  __shared__ float tile[32][33];
  int c0 = blockIdx.x * 32, r0 = blockIdx.y * 32;
  int tx = threadIdx.x & 31, ty = threadIdx.x >> 5;
  for (int i = 0; i < 4; ++i)
    tile[ty + i * 8][tx] = in[(size_t)(r0 + ty + i * 8) * cols + c0 + tx];
  __syncthreads();
  for (int i = 0; i < 4; ++i)
    out[(size_t)(c0 + ty + i * 8) * rows + r0 + tx] = f2bf(tile[tx][ty + i * 8]);
}

// ---------------- WqkT hi/lo: [128 n][2048 k] from Wq,Wk [2048][64] ----------------
__global__ __launch_bounds__(256) void k_build_wqkt(const float* __restrict__ Wq,
    const float* __restrict__ Wk, unsigned short* __restrict__ hiT,
    unsigned short* __restrict__ loT) {
  __shared__ float tile[32][33];
  int k0 = blockIdx.x * 32, n0 = blockIdx.y * 32;
  const float* W = (n0 < 64) ? Wq : Wk;
  int nb = n0 & 63;
  int tx = threadIdx.x & 31, ty = threadIdx.x >> 5;
  for (int i = 0; i < 4; ++i)
    tile[ty + i * 8][tx] = W[(size_t)(k0 + ty + i * 8) * R_ + nb + tx];
  __syncthreads();
  for (int i = 0; i < 4; ++i) {
    float v = tile[tx][ty + i * 8];
    unsigned short h = f2bf(v);
    size_t idx = (size_t)(n0 + ty + i * 8) * H_ + k0 + tx;
    hiT[idx] = h;
    loT[idx] = f2bf(v - bf2f(h));
  }
}

// ---------------- WoT_eff[n][r] = Wo[h1(r)][n] + Wo[h1(r)+128][n], bf16 ----------------
__global__ __launch_bounds__(256) void k_build_wot(const float* __restrict__ Wo,
                                                   unsigned short* __restrict__ WoT) {
  __shared__ float tile[32][33];
  int n0 = blockIdx.x * 32, r0 = blockIdx.y * 32;
  int h1b = 256 * (r0 >> 7) + (r0 & 127);
  int tx = threadIdx.x & 31, ty = threadIdx.x >> 5;
  for (int i = 0; i < 4; ++i) {
    int dr = ty + i * 8;
    tile[dr][tx] = Wo[(size_t)(h1b + dr) * H_ + n0 + tx] +
                   Wo[(size_t)(h1b + 128 + dr) * H_ + n0 + tx];
  }
  __syncthreads();
  for (int i = 0; i < 4; ++i)
    WoT[(size_t)(n0 + ty + i * 8) * DKV_ + r0 + tx] = f2bf(tile[tx][ty + i * 8]);
}

// ---------------- q/k projection via split-bf16 MFMA; 3-buffer counted-vmcnt pipeline ----------------
__global__ __launch_bounds__(256) void k_qk_mfma(
    const unsigned short* __restrict__ Ahi, const unsigned short* __restrict__ Alo,
    const unsigned short* __restrict__ Bhi, const unsigned short* __restrict__ Blo,
    unsigned short* __restrict__ qkh, unsigned short* __restrict__ qkl) {
  // per-buffer layout: AsH[0,2K) AsL[2K,4K) BsH[4K,12K) BsL[12K,20K)
  constexpr int TQK = 20480;
  __shared__ __attribute__((aligned(16))) char lds[3 * TQK];
  int m0 = blockIdx.x * 32;
  int t = threadIdx.x;
  int lane = t & 63, wave = t >> 6;
  int lr = lane & 15, kb = (lane >> 4) << 4;

  auto stage = [&](int kt, int buf) {
    int k0 = kt << 5;
    char* base = &lds[buf * TQK];
    {  // A hi (waves 0,1) / lo (waves 2,3): 128 chunks each
      int q = t & 127;
      int L = q >> 3;
      int slot = (q & 7) ^ (L & 7);
      int m = (L << 1) | (slot >> 2);
      int ke = (slot & 3) << 3;
      const unsigned short* src =
          (t < 128 ? Ahi : Alo) + (size_t)(m0 + m) * H_ + k0 + ke;
      gl_lds16(src, base + (t < 128 ? 0 : 2048) + q * 16);
    }
#pragma unroll
    for (int c = 0; c < 2; ++c) {  // B hi: 512 chunks
      int q = c * 256 + t;
      int L = q >> 3;
      int slot = (q & 7) ^ (L & 7);
      int n = (L << 1) | (slot >> 2);
      int ke = (slot & 3) << 3;
      gl_lds16(Bhi + (size_t)n * H_ + k0 + ke, base + 4096 + q * 16);
    }
#pragma unroll
    for (int c = 0; c < 2; ++c) {  // B lo: 512 chunks
      int q = c * 256 + t;
      int L = q >> 3;
      int slot = (q & 7) ^ (L & 7);
      int n = (L << 1) | (slot >> 2);
      int ke = (slot & 3) << 3;
      gl_lds16(Blo + (size_t)n * H_ + k0 + ke, base + 12288 + q * 16);
    }
  };

  f32x4v acc[2][2] = {};
  stage(0, 0);
  stage(1, 1);
  int cur = 0, nxt = 2;
  for (int kt = 0; kt < 64; ++kt) {
    __builtin_amdgcn_sched_barrier(0);
    if (kt < 63) asm volatile("s_waitcnt vmcnt(5)" ::: "memory");
    else asm volatile("s_waitcnt vmcnt(0)" ::: "memory");
    __builtin_amdgcn_s_barrier();
    __builtin_amdgcn_sched_barrier(0);
    if (kt + 2 < 64) stage(kt + 2, nxt);
    const char* base = &lds[cur * TQK];
    s16x8 ah[2], al[2], bh[2], bl[2];
#pragma unroll
    for (int m = 0; m < 2; ++m) {
      int o = swz_off(m * 16 + lr, kb);
      ah[m] = *(const s16x8*)(base + o);
      al[m] = *(const s16x8*)(base + 2048 + o);
    }
#pragma unroll
    for (int n = 0; n < 2; ++n) {
      int o = swz_off(wave * 32 + n * 16 + lr, kb);
      bh[n] = *(const s16x8*)(base + 4096 + o);
      bl[n] = *(const s16x8*)(base + 12288 + o);
    }
    __builtin_amdgcn_s_setprio(1);
#pragma unroll
    for (int m = 0; m < 2; ++m)
#pragma unroll
      for (int n = 0; n < 2; ++n) {
        acc[m][n] = __builtin_amdgcn_mfma_f32_16x16x32_bf16(ah[m], bh[n], acc[m][n], 0, 0, 0);
        acc[m][n] = __builtin_amdgcn_mfma_f32_16x16x32_bf16(ah[m], bl[n], acc[m][n], 0, 0, 0);
        acc[m][n] = __builtin_amdgcn_mfma_f32_16x16x32_bf16(al[m], bh[n], acc[m][n], 0, 0, 0);
      }
    __builtin_amdgcn_s_setprio(0);
    cur = (cur == 2) ? 0 : cur + 1;
    nxt = (nxt == 2) ? 0 : nxt + 1;
  }
  for (int m = 0; m < 2; ++m) {
    int lrow = m * 16 + ((lane >> 4) << 2);
    for (int n = 0; n < 2; ++n) {
      int lcol = wave * 32 + n * 16 + lr;
      for (int r = 0; r < 4; ++r) {
        float v = acc[m][n][r];
        unsigned short h = f2bf(v);
        size_t idx = (size_t)(m0 + lrow + r) * 128 + lcol;
        qkh[idx] = h;
        qkl[idx] = f2bf(v - bf2f(h));
      }
    }
  }
}

// ---------------- fused scores+exp+rowsum+PV ----------------
// Per block: 64 query rows (m0) x 256 d-slice (d0), batch z. Loop j in steps
// of 32 (causal: j < m0+64). Per step, 3-buffer pipelined staging of
// k-tile(8KB) + V-tile(16KB) via gl_lds (LPS=3, counted vmcnt), QK^T from reg
// q-frags x LDS k-frags (3-term hi/lo split), exp+mask in-reg, P->LDS (swz),
// PV from LDS P x LDS V. Rowsums in registers; ctx scaled by 1/rowsum at end.
// No probs materialization, no separate rowsum pass, no softmax-max needed
// (scores O(1); matches existing plain-exp numerics).
__global__ __launch_bounds__(512, 4) void k_attn_fused(
    const unsigned short* __restrict__ qkh, const unsigned short* __restrict__ qkl,
    const unsigned short* __restrict__ VT, unsigned short* __restrict__ ctx) {
  constexpr int TILEB = 24576;  // k: 4x2KB subtiles, V: 16KB
  __shared__ __attribute__((aligned(16))) char lds[3 * TILEB + 4096 + 256];
  char* Pt = &lds[3 * TILEB];
  float* rs = (float*)&lds[3 * TILEB + 4096];

  int t = threadIdx.x;
  int gx = gridDim.x;  // 32
  int x = blockIdx.x;
  int bx = (x & 1) ? (gx - 1 - (x >> 1)) : (x >> 1);  // heavy+light pairing
  if (blockIdx.z & 2) bx = gx - 1 - bx;               // stride-256 pairing
  int z = blockIdx.z;
  int m0 = bx * 64, d0 = blockIdx.y * 256;

  int lane = t & 63, wave = t >> 6;
  int sm = wave >> 1, sn = wave & 1;  // QK^T role: S-frag (16i x 16j)
  int wr = wave >> 2, wc = wave & 3;  // PV role: 32i x 64d
  int kb = (lane >> 4) << 4;

  const unsigned short* qh = qkh + (size_t)z * S_ * 128;
  const unsigned short* ql = qkl + (size_t)z * S_ * 128;

  // q A-frags (row = lane&15, rank chunk = (lane>>4)*8), hi/lo x 2 rank-steps
  s16x8 qfh[2], qfl[2];
  {
    size_t rq = (size_t)(m0 + sm * 16 + (lane & 15)) * 128 + ((lane >> 4) << 3);
    qfh[0] = *(const s16x8*)(qh + rq);
    qfh[1] = *(const s16x8*)(qh + rq + 32);
    qfl[0] = *(const s16x8*)(ql + rq);
    qfl[1] = *(const s16x8*)(ql + rq + 32);
  }

  auto stage = [&](int kt, int buf) {
    int j0 = kt << 5;
    char* base = &lds[buf * TILEB];
    {  // k rows [32][32] x {hi,lo} x {rank0,rank32}; t>>7 picks subtile
      int q = t & 127;
      int L = q >> 3;
      int slot = (q & 7) ^ (L & 7);
      int jr = (L << 1) | (slot >> 2);
      int ke = (slot & 3) << 3;
      int sub = t >> 7;
      const unsigned short* src = ((sub < 2) ? qh : ql) +
          (size_t)(j0 + jr) * 128 + 64 + ((sub & 1) << 5) + ke;
      gl_lds16(src, base + sub * 2048 + q * 16);
    }
    char* vb = base + 8192;  // V tile [256 d][32 j]
#pragma unroll
    for (int c = 0; c < 2; ++c) {
      int q = c * 512 + t;
      int L = q >> 3;
      int slot = (q & 7) ^ (L & 7);
      int dr = (L << 1) | (slot >> 2);
      int ke = (slot & 3) << 3;
      gl_lds16(VT + (size_t)(d0 + dr) * (B_ * S_) + (size_t)z * S_ + j0 + ke,
               vb + q * 16);
    }
  };

  if (t < 64) rs[t] = 0.f;
  int NT = (m0 + 64) >> 5;  // causal j extent
  stage(0, 0);
  stage(1, 1);

  int jrow = sn * 16 + (lane & 15);
  int koffs = swz_off(jrow, kb);
  int paoff[2], voff[4];
#pragma unroll
  for (int mf = 0; mf < 2; ++mf)
    paoff[mf] = swz_off(wr * 32 + mf * 16 + (lane & 15), kb);
#pragma unroll
  for (int nf = 0; nf < 4; ++nf)
    voff[nf] = swz_off(wc * 64 + nf * 16 + (lane & 15), kb);

  float ps[4] = {0.f, 0.f, 0.f, 0.f};
  f32x4v accp[2][4] = {};
  int prow = sm * 16 + ((lane >> 4) << 2);  // P-write local row base
  int pcol = sn * 16 + (lane & 15);         // P-write local col

  int cur = 0, nxt = 2;
  for (int kt = 0; kt < NT; ++kt) {
    __builtin_amdgcn_sched_barrier(0);
    if (kt + 1 < NT) asm volatile("s_waitcnt vmcnt(3) lgkmcnt(0)" ::: "memory");
    else asm volatile("s_waitcnt vmcnt(0) lgkmcnt(0)" ::: "memory");
    __builtin_amdgcn_s_barrier();
    __builtin_amdgcn_sched_barrier(0);
    if (kt + 2 < NT) stage(kt + 2, nxt);
    const char* base = &lds[cur * TILEB];
    // ---- QK^T: S-frag 16x16 per wave, 3-term hi/lo x 2 rank-steps ----
    s16x8 kh[2], kl[2];
    kh[0] = *(const s16x8*)(base + koffs);
    kh[1] = *(const s16x8*)(base + 2048 + koffs);
    kl[0] = *(const s16x8*)(base + 4096 + koffs);
    kl[1] = *(const s16x8*)(base + 6144 + koffs);
    f32x4v s = {};
#pragma unroll
    for (int ks = 0; ks < 2; ++ks) {
      s = __builtin_amdgcn_mfma_f32_16x16x32_bf16(qfh[ks], kh[ks], s, 0, 0, 0);
      s = __builtin_amdgcn_mfma_f32_16x16x32_bf16(qfh[ks], kl[ks], s, 0, 0, 0);
      s = __builtin_amdgcn_mfma_f32_16x16x32_bf16(qfl[ks], kh[ks], s, 0, 0, 0);
    }
    // ---- exp + causal mask + rowsum + P write ----
    int jg = (kt << 5) + pcol;
    int ig = m0 + prow;
#pragma unroll
    for (int r = 0; r < 4; ++r) {
      float p = (jg <= ig + r) ? __expf(s[r]) : 0.f;
      ps[r] += p;
      *(unsigned short*)(Pt + swz_off(prow + r, pcol * 2)) = f2bf(p);
    }
    __builtin_amdgcn_sched_barrier(0);
    asm volatile("s_waitcnt lgkmcnt(0)" ::: "memory");
    __builtin_amdgcn_s_barrier();
    __builtin_amdgcn_sched_barrier(0);
    // ---- PV: 32i x 64d per wave, K=32 ----
    s16x8 pa[2], vf[4];
#pragma unroll
    for (int mf = 0; mf < 2; ++mf) pa[mf] = *(const s16x8*)(Pt + paoff[mf]);
    const char* vbase = base + 8192;
#pragma unroll
    for (int nf = 0; nf < 4; ++nf) vf[nf] = *(const s16x8*)(vbase + voff[nf]);
    __builtin_amdgcn_s_setprio(1);
#pragma unroll
    for (int mf = 0; mf < 2; ++mf)
#pragma unroll
      for (int nf = 0; nf < 4; ++nf)
        accp[mf][nf] =
            __builtin_amdgcn_mfma_f32_16x16x32_bf16(pa[mf], vf[nf], accp[mf][nf], 0, 0, 0);
    __builtin_amdgcn_s_setprio(0);
    cur = (cur == 2) ? 0 : cur + 1;
    nxt = (nxt == 2) ? 0 : nxt + 1;
  }

  // ---- rowsum reduce (16 j-lanes) -> LDS ----
#pragma unroll
  for (int r = 0; r < 4; ++r) {
    float v = ps[r];
    for (int msk = 1; msk < 16; msk <<= 1) v += __shfl_xor(v, msk, 64);
    if ((lane & 15) == 0) atomicAdd(&rs[prow + r], v);
  }
  __syncthreads();

  // ---- scale + write ctx ----
  unsigned short* Cp = ctx + (size_t)(z * S_ + m0) * DKV_ + d0;
#pragma unroll
  for (int mf = 0; mf < 2; ++mf) {
    int lr0 = wr * 32 + mf * 16 + ((lane >> 4) << 2);
#pragma unroll
    for (int nf = 0; nf < 4; ++nf) {
      int lc = wc * 64 + nf * 16 + (lane & 15);
#pragma unroll
      for (int r = 0; r < 4; ++r) {
        float sc = 1.f / rs[lr0 + r];
        Cp[(size_t)(lr0 + r) * DKV_ + lc] = f2bf(accp[mf][nf][r] * sc);
      }
    }
  }
}

// ---------------- pipelined bf16 MFMA GEMM (wave 64x64) ----------------
// C[m][n] = sum_k A[m][k] * BT[n][k]; 512 threads, 8 waves 4Mx2N, BK=32,
// 3-buffer LDS pipeline, counted vmcnt depth-2, swizzled LDS.
template <int BM, int BN, bool TRANS_OUT, bool OUT_BF16>
__global__ __launch_bounds__(512, 4) void k_gemm256(
    const unsigned short* __restrict__ A, int lda,
    const unsigned short* __restrict__ BT, int ldbt,
    void* __restrict__ C, int ldc, int K) {
  constexpr int ABYTES = BM * 64;
  constexpr int BBYTES = BN * 64;
  constexpr int TILEB = ABYTES + BBYTES;
  constexpr int WARPS_M = 4;
  constexpr int WARPS_N = 2;
  constexpr int WM = BM / WARPS_M;
  constexpr int WN = BN / WARPS_N;
  constexpr int MF = WM / 16;
  constexpr int NF = WN / 16;
  constexpr int LPS = BM / 128 + BN / 128;
  __shared__ __attribute__((aligned(16))) char lds[3 * TILEB];

  int t = threadIdx.x;
  int gx = gridDim.x;
  int id = blockIdx.y * gx + blockIdx.x;
  int cpx = gx >> 3;
  int xcd = id & 7, rr = id >> 3;
  int bx = xcd * cpx + rr % cpx;  // contiguous bx-chunk per XCD
  int by = rr / cpx;
  int m0 = bx * BM, n0 = by * BN;

  const unsigned short* Ab = A + (size_t)m0 * lda;
  const unsigned short* Bb = BT + (size_t)n0 * ldbt;

  int lane = t & 63, wave = t >> 6;
  int wr = wave / WARPS_N, wc = wave % WARPS_N;
  int kb = (lane >> 4) << 4;
  int aoff[MF], boff[NF];
#pragma unroll
  for (int mf = 0; mf < MF; ++mf)
    aoff[mf] = swz_off(wr * WM + mf * 16 + (lane & 15), kb);
#pragma unroll
  for (int nf = 0; nf < NF; ++nf)
    boff[nf] = swz_off(wc * WN + nf * 16 + (lane & 15), kb);

  int NT = K >> 5;

  auto stage = [&](int kt, int buf) {
    int k0 = kt << 5;
    char* la = &lds[buf * TILEB];
    char* lb = la + ABYTES;
#pragma unroll
    for (int c = 0; c < BM / 128; ++c) {
      int q = c * 512 + t;
      int L = q >> 3;
      int slot = (q & 7) ^ (L & 7);
      int m = (L << 1) | (slot >> 2);
      int ke = (slot & 3) << 3;
      gl_lds16(Ab + (size_t)m * lda + k0 + ke, la + q * 16);
    }
#pragma unroll
    for (int c = 0; c < BN / 128; ++c) {
      int q = c * 512 + t;
      int L = q >> 3;
      int slot = (q & 7) ^ (L & 7);
      int n = (L << 1) | (slot >> 2);
      int ke = (slot & 3) << 3;
      gl_lds16(Bb + (size_t)n * ldbt + k0 + ke, lb + q * 16);
    }
  };

  f32x4v acc[MF][NF] = {};
  stage(0, 0);
  if (NT > 1) stage(1, 1);
  int cur = 0, nxt = 2;
  for (int kt = 0; kt < NT; ++kt) {
    __builtin_amdgcn_sched_barrier(0);
    if (kt + 1 < NT) {
      if constexpr (LPS == 2) asm volatile("s_waitcnt vmcnt(2)" ::: "memory");
      else asm volatile("s_waitcnt vmcnt(3)" ::: "memory");
    } else {
      asm volatile("s_waitcnt vmcnt(0)" ::: "memory");
    }
    __builtin_amdgcn_s_barrier();
    __builtin_amdgcn_sched_barrier(0);
    if (kt + 2 < NT) stage(kt + 2, nxt);
    const char* la = &lds[cur * TILEB];
    const char* lb = la + ABYTES;
    s16x8 af[MF], bf[NF];
#pragma unroll
    for (int mf = 0; mf < MF; ++mf) af[mf] = *(const s16x8*)(la + aoff[mf]);
#pragma unroll
    for (int nf = 0; nf < NF; ++nf) bf[nf] = *(const s16x8*)(lb + boff[nf]);
    __builtin_amdgcn_s_setprio(1);
#pragma unroll
    for (int mf = 0; mf < MF; ++mf)
#pragma unroll
      for (int nf = 0; nf < NF; ++nf)
        acc[mf][nf] =
            __builtin_amdgcn_mfma_f32_16x16x32_bf16(af[mf], bf[nf], acc[mf][nf], 0, 0, 0);
    __builtin_amdgcn_s_setprio(0);
    cur = (cur == 2) ? 0 : cur + 1;
    nxt = (nxt == 2) ? 0 : nxt + 1;
  }

#pragma unroll
  for (int mf = 0; mf < MF; ++mf) {
    int lrow = wr * WM + mf * 16 + ((lane >> 4) << 2);
#pragma unroll
    for (int nf = 0; nf < NF; ++nf) {
      int lcol = wc * WN + nf * 16 + (lane & 15);
      f32x4v v = acc[mf][nf];
      if (TRANS_OUT) {
        ushort4 o;
        o.x = f2bf(v[0]); o.y = f2bf(v[1]); o.z = f2bf(v[2]); o.w = f2bf(v[3]);
        unsigned short* Cp = (unsigned short*)C;
        *(ushort4*)&Cp[(size_t)(n0 + lcol) * ldc + m0 + lrow] = o;
      } else {
#pragma unroll
        for (int r = 0; r < 4; ++r) {
          if (OUT_BF16) {
            unsigned short* Cp = (unsigned short*)C;
            Cp[(size_t)(m0 + lrow + r) * ldc + n0 + lcol] = f2bf(v[r]);
          } else {
            float* Cp = (float*)C;
            Cp[(size_t)(m0 + lrow + r) * ldc + n0 + lcol] = v[r];
          }
        }
      }
    }
  }
}

extern "C" void kernel_launch(void* const* d_in, const int* in_sizes, int n_in,
                              void* d_out, int out_size, void* d_ws, size_t ws_size,
                              hipStream_t stream) {
  const float* hs = (const float*)d_in[0];
  const float* Wq = (const float*)d_in[2];
  const float* Wk = (const float*)d_in[3];
  const float* Wv = (const float*)d_in[4];
  const float* Wo = (const float*)d_in[5];
  float* out = (float*)d_out;

  char* w = (char*)d_ws;
  unsigned short* hsb = (unsigned short*)w; w += (size_t)B_ * S_ * H_ * 2;
  unsigned short* hsl = (unsigned short*)w; w += (size_t)B_ * S_ * H_ * 2;
  unsigned short* WvT = (unsigned short*)w; w += (size_t)DKV_ * H_ * 2;
  unsigned short* WoT = (unsigned short*)w; w += (size_t)H_ * DKV_ * 2;
  unsigned short* WqkTh = (unsigned short*)w; w += (size_t)128 * H_ * 2;
  unsigned short* WqkTl = (unsigned short*)w; w += (size_t)128 * H_ * 2;
  unsigned short* VT  = (unsigned short*)w; w += (size_t)DKV_ * B_ * S_ * 2;
  unsigned short* ctx = (unsigned short*)w; w += (size_t)B_ * S_ * DKV_ * 2;
  unsigned short* qkh = (unsigned short*)w; w += (size_t)B_ * S_ * 128 * 2;
  unsigned short* qkl = (unsigned short*)w; w += (size_t)B_ * S_ * 128 * 2;

  // 1) hs -> bf16 hi + lo
  k_f32_to_bf16x2<<<(B_ * S_ * H_ / 4 + 255) / 256, 256, 0, stream>>>(
      hs, hsb, hsl, B_ * S_ * H_ / 4);
  // 2) WvT = Wv^T bf16
  k_transpose_bf16<<<dim3(DKV_ / 32, H_ / 32), 256, 0, stream>>>(Wv, WvT, H_, DKV_);
  // 3) WoT_eff
  k_build_wot<<<dim3(H_ / 32, DKV_ / 32), 256, 0, stream>>>(Wo, WoT);
  // 4) WqkT hi/lo
  k_build_wqkt<<<dim3(H_ / 32, 4), 256, 0, stream>>>(Wq, Wk, WqkTh, WqkTl);
  // 5) q/k projection -> bf16 hi/lo q,k (pipelined)
  k_qk_mfma<<<B_ * S_ / 32, 256, 0, stream>>>(hsb, hsl, WqkTh, WqkTl, qkh, qkl);
  // 6) V projection (transposed epilogue -> VT): BM=256xBN=128, wave 64x64
  k_gemm256<256, 128, true, true>
      <<<dim3(B_ * S_ / 256, DKV_ / 128), 512, 0, stream>>>(
      hsb, H_, WvT, H_, VT, B_ * S_, H_);
  // 7) fused scores+exp+rowsum+PV -> ctx (512 blocks, 2/CU, paired causal)
  k_attn_fused<<<dim3(32, 4, B_), 512, 0, stream>>>(qkh, qkl, VT, ctx);
  // 8) out = ctx @ WoT^T (fp32 out): BM=256xBN=128, wave 64x64
  k_gemm256<256, 128, false, false>
      <<<dim3(B_ * S_ / 256, H_ / 128), 512, 0, stream>>>(
      ctx, DKV_, WoT, DKV_, out, H_, DKV_);
}